// Round 1
// baseline (650.220 us; speedup 1.0000x reference)
//
#include <hip/hip_runtime.h>
#include <cstddef>

// Problem constants (B=8, N=2048, C=256, H=4, D=64, Hid=1024)
#define RR 16384   // B*N rows
#define CC 256
#define HID 1024
#define NN 2048

// ---------------------------------------------------------------------------
// LayerNorm over last dim (256). One wave per row, 4 rows per block.
__global__ __launch_bounds__(256) void ln_kernel(const float* __restrict__ x,
    const float* __restrict__ g, const float* __restrict__ b,
    float* __restrict__ out) {
  const int wave = threadIdx.x >> 6, lane = threadIdx.x & 63;
  const int row = (blockIdx.x << 2) + wave;
  const float4 v = ((const float4*)(x + (size_t)row * CC))[lane];
  float s1 = v.x + v.y + v.z + v.w;
  float s2 = v.x * v.x + v.y * v.y + v.z * v.z + v.w * v.w;
#pragma unroll
  for (int o = 32; o > 0; o >>= 1) {
    s1 += __shfl_xor(s1, o);
    s2 += __shfl_xor(s2, o);
  }
  const float mu = s1 * (1.0f / CC);
  const float var = s2 * (1.0f / CC) - mu * mu;
  const float rs = 1.0f / sqrtf(var + 1e-5f);
  const float4 gg = ((const float4*)g)[lane];
  const float4 bb = ((const float4*)b)[lane];
  float4 o4;
  o4.x = (v.x - mu) * rs * gg.x + bb.x;
  o4.y = (v.y - mu) * rs * gg.y + bb.y;
  o4.z = (v.z - mu) * rs * gg.z + bb.z;
  o4.w = (v.w - mu) * rs * gg.w + bb.w;
  ((float4*)(out + (size_t)row * CC))[lane] = o4;
}

// ---------------------------------------------------------------------------
// Y[r,o] = sum_k A[r,k]*W[o,k]  (+ resid[r,o] if resid != nullptr)
// fp32 VALU GEMM. 64x64 tile per 256-thread block, 4x4 per thread, KB=16.
// LDS rows padded to 68 floats (272B = 17*16B): float4-aligned, 2-way banks.
__global__ __launch_bounds__(256) void gemm_f32(const float* __restrict__ A,
    const float* __restrict__ W, const float* __restrict__ resid,
    float* __restrict__ Y, int K, int O) {
  __shared__ float As[16][68];
  __shared__ float Ws[16][68];
  const int tid = threadIdx.x;
  const int tx = tid & 15, ty = tid >> 4;
  const int r0 = blockIdx.y << 6, o0 = blockIdx.x << 6;
  const int lrow = tid >> 2, lk4 = (tid & 3) << 2;
  const float* Ap = A + (size_t)(r0 + lrow) * K + lk4;
  const float* Wp = W + (size_t)(o0 + lrow) * K + lk4;
  float acc[4][4] = {};
  for (int k0 = 0; k0 < K; k0 += 16) {
    const float4 a = *(const float4*)(Ap + k0);
    const float4 w = *(const float4*)(Wp + k0);
    __syncthreads();
    As[lk4 + 0][lrow] = a.x; As[lk4 + 1][lrow] = a.y;
    As[lk4 + 2][lrow] = a.z; As[lk4 + 3][lrow] = a.w;
    Ws[lk4 + 0][lrow] = w.x; Ws[lk4 + 1][lrow] = w.y;
    Ws[lk4 + 2][lrow] = w.z; Ws[lk4 + 3][lrow] = w.w;
    __syncthreads();
#pragma unroll
    for (int kk = 0; kk < 16; ++kk) {
      const float4 av = *(const float4*)&As[kk][ty << 2];
      const float4 wv = *(const float4*)&Ws[kk][tx << 2];
      acc[0][0] += av.x * wv.x; acc[0][1] += av.x * wv.y;
      acc[0][2] += av.x * wv.z; acc[0][3] += av.x * wv.w;
      acc[1][0] += av.y * wv.x; acc[1][1] += av.y * wv.y;
      acc[1][2] += av.y * wv.z; acc[1][3] += av.y * wv.w;
      acc[2][0] += av.z * wv.x; acc[2][1] += av.z * wv.y;
      acc[2][2] += av.z * wv.z; acc[2][3] += av.z * wv.w;
      acc[3][0] += av.w * wv.x; acc[3][1] += av.w * wv.y;
      acc[3][2] += av.w * wv.z; acc[3][3] += av.w * wv.w;
    }
  }
#pragma unroll
  for (int i = 0; i < 4; ++i) {
    const size_t idx = (size_t)(r0 + (ty << 2) + i) * O + o0 + (tx << 2);
    float4 v = make_float4(acc[i][0], acc[i][1], acc[i][2], acc[i][3]);
    if (resid) {
      const float4 rr = *(const float4*)(resid + idx);
      v.x += rr.x; v.y += rr.y; v.z += rr.z; v.w += rr.w;
    }
    *(float4*)(Y + idx) = v;
  }
}

// ---------------------------------------------------------------------------
// BatchNorm stats pass 1: per-block partial sum / sumsq per channel.
// 256 blocks x 64 rows. Thread t owns channels {t, t+256, ...}. Deterministic.
template <int O>
__global__ __launch_bounds__(256) void bn_stats1(const float* __restrict__ Y,
    float* __restrict__ p1, float* __restrict__ p2) {
  const int t = threadIdx.x;
  const int r0 = blockIdx.x << 6;
  constexpr int NCH = O / 256;
  float s1[NCH] = {}, s2[NCH] = {};
  for (int r = r0; r < r0 + 64; ++r) {
    const float* row = Y + (size_t)r * O;
#pragma unroll
    for (int c = 0; c < NCH; ++c) {
      const float y = row[t + (c << 8)];
      s1[c] += y;
      s2[c] += y * y;
    }
  }
#pragma unroll
  for (int c = 0; c < NCH; ++c) {
    p1[(size_t)blockIdx.x * O + t + (c << 8)] = s1[c];
    p2[(size_t)blockIdx.x * O + t + (c << 8)] = s2[c];
  }
}

// pass 2: finalize mean + rsqrt(var+eps). One thread per channel.
__global__ __launch_bounds__(256) void bn_stats2(const float* __restrict__ p1,
    const float* __restrict__ p2, float* __restrict__ mu,
    float* __restrict__ rinv, int O) {
  const int o = blockIdx.x * 256 + threadIdx.x;
  float s1 = 0.f, s2 = 0.f;
  for (int j = 0; j < 256; ++j) {
    s1 += p1[(size_t)j * O + o];
    s2 += p2[(size_t)j * O + o];
  }
  const float m = s1 * (1.0f / 16384.f);
  const float v = s2 * (1.0f / 16384.f) - m * m;
  mu[o] = m;
  rinv[o] = 1.0f / sqrtf(v + 1e-5f);
}

// Apply BN affine + Heaviside spike. Either writes spikes to S (may alias Y)
// or adds spikes into addOut (final residual).
__global__ __launch_bounds__(256) void bn_spike(const float* __restrict__ Y,
    const float* __restrict__ mu, const float* __restrict__ rinv,
    const float* __restrict__ g, const float* __restrict__ b,
    float* __restrict__ S, float* __restrict__ addOut, int O) {
  const int i = blockIdx.x * 256 + threadIdx.x;  // over R*O/4 float4s
  const int c = (i << 2) & (O - 1);              // O is a power of two
  const float4 y = ((const float4*)Y)[i];
  const float4 m4 = *(const float4*)(mu + c);
  const float4 r4 = *(const float4*)(rinv + c);
  const float4 g4 = *(const float4*)(g + c);
  const float4 b4 = *(const float4*)(b + c);
  float4 s;
  s.x = ((y.x - m4.x) * r4.x * g4.x + b4.x >= 1.0f) ? 1.0f : 0.0f;
  s.y = ((y.y - m4.y) * r4.y * g4.y + b4.y >= 1.0f) ? 1.0f : 0.0f;
  s.z = ((y.z - m4.z) * r4.z * g4.z + b4.z >= 1.0f) ? 1.0f : 0.0f;
  s.w = ((y.w - m4.w) * r4.w * g4.w + b4.w >= 1.0f) ? 1.0f : 0.0f;
  if (addOut) {
    float4 o4 = ((const float4*)addOut)[i];
    o4.x += s.x; o4.y += s.y; o4.z += s.z; o4.w += s.w;
    ((float4*)addOut)[i] = o4;
  } else {
    ((float4*)S)[i] = s;
  }
}

// ---------------------------------------------------------------------------
// M[b,h] = K^T V (64x64), split over n into 8 partials per (b,h).
// Exact: k,v are {0,1}, integer accum < 2^24 in fp32.
__global__ __launch_bounds__(256) void attn_kv(const float* __restrict__ Ksp,
    const float* __restrict__ Vsp, float* __restrict__ Mpart) {
  const int bh = blockIdx.x, sp = blockIdx.y;
  const int b = bh >> 2, h = bh & 3;
  const int t = threadIdx.x;
  const int gq = t >> 6, e = t & 63;
  const size_t base = (size_t)b * NN * CC + (h << 6);
  __shared__ float ks[16][64], vs[16][64];
  float acc[16] = {};
  const int lrow = t >> 4, lf = (t & 15) << 2;
  for (int n0 = sp * 256; n0 < sp * 256 + 256; n0 += 16) {
    const float4 kq = *(const float4*)(Ksp + base + (size_t)(n0 + lrow) * CC + lf);
    const float4 vq = *(const float4*)(Vsp + base + (size_t)(n0 + lrow) * CC + lf);
    __syncthreads();
    *(float4*)&ks[lrow][lf] = kq;
    *(float4*)&vs[lrow][lf] = vq;
    __syncthreads();
#pragma unroll
    for (int nn = 0; nn < 16; ++nn) {
      const float vv = vs[nn][e];
#pragma unroll
      for (int i = 0; i < 16; ++i) acc[i] += ks[nn][(gq << 4) + i] * vv;
    }
  }
  float* mp = Mpart + (((size_t)bh << 3) + sp) * 4096;
#pragma unroll
  for (int i = 0; i < 16; ++i) mp[((gq << 4) + i) * 64 + e] = acc[i];
}

__global__ __launch_bounds__(256) void attn_kv_reduce(
    const float* __restrict__ Mpart, float* __restrict__ M) {
  const int i = blockIdx.x * 256 + threadIdx.x;  // 32*4096 total
  const int bh = i >> 12, j = i & 4095;
  float s = 0.f;
#pragma unroll
  for (int sp = 0; sp < 8; ++sp)
    s += Mpart[(((size_t)((bh << 3) + sp)) << 12) + j];
  M[i] = s;
}

// o[r, h*64+e] = 0.125 * sum_d q[r, h*64+d] * M[b,h][d][e]
__global__ __launch_bounds__(256) void attn_qm(const float* __restrict__ Qsp,
    const float* __restrict__ M, float* __restrict__ Oout) {
  const int h = blockIdx.x;
  const int r0 = blockIdx.y << 6;
  const int b = blockIdx.y >> 5;  // 32 row-chunks per batch element
  const int t = threadIdx.x;
  const int e = t & 63, rg = t >> 6;
  __shared__ float Ms[64][64];
  __shared__ float qs[64][64];
  const float* Mb = M + ((size_t)(b * 4 + h) << 12);
  for (int i = t; i < 4096; i += 256) ((float*)Ms)[i] = Mb[i];
  for (int rl = rg; rl < 64; rl += 4)
    qs[rl][e] = Qsp[(size_t)(r0 + rl) * CC + (h << 6) + e];
  __syncthreads();
  for (int rl = rg; rl < 64; rl += 4) {
    float acc = 0.f;
#pragma unroll
    for (int d = 0; d < 64; ++d) acc += qs[rl][d] * Ms[d][e];
    Oout[(size_t)(r0 + rl) * CC + (h << 6) + e] = 0.125f * acc;
  }
}

// ---------------------------------------------------------------------------
extern "C" void kernel_launch(void* const* d_in, const int* in_sizes, int n_in,
                              void* d_out, int out_size, void* d_ws,
                              size_t ws_size, hipStream_t stream) {
  const float* x    = (const float*)d_in[0];
  const float* ln1g = (const float*)d_in[1];
  const float* ln1b = (const float*)d_in[2];
  const float* wq   = (const float*)d_in[3];
  const float* qg   = (const float*)d_in[4];
  const float* qb   = (const float*)d_in[5];
  const float* wk   = (const float*)d_in[6];
  const float* kg   = (const float*)d_in[7];
  const float* kb   = (const float*)d_in[8];
  const float* wv   = (const float*)d_in[9];
  const float* vg   = (const float*)d_in[10];
  const float* vb   = (const float*)d_in[11];
  const float* wo   = (const float*)d_in[12];
  const float* ln2g = (const float*)d_in[13];
  const float* ln2b = (const float*)d_in[14];
  const float* w1   = (const float*)d_in[15];
  const float* b1g  = (const float*)d_in[16];
  const float* b1b  = (const float*)d_in[17];
  const float* w2   = (const float*)d_in[18];
  const float* b2g  = (const float*)d_in[19];
  const float* b2b  = (const float*)d_in[20];
  float* out = (float*)d_out;
  char* ws = (char*)d_ws;
  const size_t MB = 1u << 20;
  // Arena (~87.5 MB): E (R x Hid) overlays Bq/Ck/Dv which are dead by then.
  float* A     = (float*)(ws);             // R x C   (h1, then o, then h2, then y2)
  float* Bq    = (float*)(ws + 16 * MB);   // R x C   (yq -> q spikes)
  float* Ck    = (float*)(ws + 32 * MB);   // R x C   (yk -> k spikes)
  float* Dv    = (float*)(ws + 48 * MB);   // R x C   (yv -> v spikes)
  float* E     = (float*)(ws + 16 * MB);   // R x Hid (y1 -> m1 spikes), [16M,80M)
  float* p1    = (float*)(ws + 80 * MB);
  float* p2    = (float*)(ws + 81 * MB);
  float* mu    = (float*)(ws + 82 * MB);
  float* rinv  = (float*)(ws + 82 * MB + 8192);
  float* Mpart = (float*)(ws + 83 * MB);   // 32*8*4096 f32 = 4 MB
  float* Mful  = (float*)(ws + 87 * MB);   // 32*4096 f32 = 512 KB

  const dim3 blk(256);

  // 1. h1 = LN1(x)
  ln_kernel<<<RR / 4, blk, 0, stream>>>(x, ln1g, ln1b, A);
  // 2. QKV projections
  gemm_f32<<<dim3(4, 256), blk, 0, stream>>>(A, wq, nullptr, Bq, 256, 256);
  gemm_f32<<<dim3(4, 256), blk, 0, stream>>>(A, wk, nullptr, Ck, 256, 256);
  gemm_f32<<<dim3(4, 256), blk, 0, stream>>>(A, wv, nullptr, Dv, 256, 256);
  // 3. BN + spike (in place) for q, k, v
  {
    const float* gs[3] = {qg, kg, vg};
    const float* bs[3] = {qb, kb, vb};
    float* ys[3] = {Bq, Ck, Dv};
    for (int i = 0; i < 3; ++i) {
      bn_stats1<256><<<256, blk, 0, stream>>>(ys[i], p1, p2);
      bn_stats2<<<1, blk, 0, stream>>>(p1, p2, mu, rinv, 256);
      bn_spike<<<RR * 256 / 4 / 256, blk, 0, stream>>>(ys[i], mu, rinv, gs[i],
                                                       bs[i], ys[i], nullptr, 256);
    }
  }
  // 4-5. M = K^T V per (b,h)
  attn_kv<<<dim3(32, 8), blk, 0, stream>>>(Ck, Dv, Mpart);
  attn_kv_reduce<<<512, blk, 0, stream>>>(Mpart, Mful);
  // 6. o = 0.125 * q @ M   -> A
  attn_qm<<<dim3(4, RR / 64), blk, 0, stream>>>(Bq, Mful, A);
  // 7. x2 = x + o @ wo^T   -> d_out
  gemm_f32<<<dim3(4, 256), blk, 0, stream>>>(A, wo, x, out, 256, 256);
  // 8. h2 = LN2(x2)
  ln_kernel<<<RR / 4, blk, 0, stream>>>(out, ln2g, ln2b, A);
  // 9. y1 = h2 @ w1^T      -> E (R x 1024)
  gemm_f32<<<dim3(16, 256), blk, 0, stream>>>(A, w1, nullptr, E, 256, 1024);
  // 10. BN + spike m1 (in place)
  bn_stats1<1024><<<256, blk, 0, stream>>>(E, p1, p2);
  bn_stats2<<<4, blk, 0, stream>>>(p1, p2, mu, rinv, 1024);
  bn_spike<<<RR * 1024 / 4 / 256, blk, 0, stream>>>(E, mu, rinv, b1g, b1b, E,
                                                    nullptr, 1024);
  // 11. y2 = m1 @ w2^T     -> A
  gemm_f32<<<dim3(4, 256), blk, 0, stream>>>(E, w2, nullptr, A, 1024, 256);
  // 12. out += spike(BN(y2))
  bn_stats1<256><<<256, blk, 0, stream>>>(A, p1, p2);
  bn_stats2<<<1, blk, 0, stream>>>(p1, p2, mu, rinv, 256);
  bn_spike<<<RR * 256 / 4 / 256, blk, 0, stream>>>(A, mu, rinv, b2g, b2b,
                                                   nullptr, out, 256);
}

// Round 3
// 547.498 us; speedup vs baseline: 1.1876x; 1.1876x over previous
//
#include <hip/hip_runtime.h>
#include <cstddef>
#include <cstdint>

#define RR 16384   // B*N rows
#define CC 256
#define NN 2048

typedef __attribute__((ext_vector_type(8))) short short8v;
typedef __attribute__((ext_vector_type(4))) float float4v;
typedef unsigned short u16;

__device__ inline u16 f2bf(float f) {  // RNE, finite inputs only
  uint32_t u = __builtin_bit_cast(uint32_t, f);
  return (u16)((u + 0x7FFFu + ((u >> 16) & 1u)) >> 16);
}
__device__ inline float bf2f(u16 u) {
  return __builtin_bit_cast(float, (uint32_t)u << 16);
}

// ---------------------------------------------------------------------------
// LayerNorm (fp32 out) — used for LN1 feeding the fp32 QKV GEMMs.
__global__ __launch_bounds__(256) void ln_kernel(const float* __restrict__ x,
    const float* __restrict__ g, const float* __restrict__ b,
    float* __restrict__ out) {
  const int wave = threadIdx.x >> 6, lane = threadIdx.x & 63;
  const int row = (blockIdx.x << 2) + wave;
  const float4 v = ((const float4*)(x + (size_t)row * CC))[lane];
  float s1 = v.x + v.y + v.z + v.w;
  float s2 = v.x * v.x + v.y * v.y + v.z * v.z + v.w * v.w;
#pragma unroll
  for (int o = 32; o > 0; o >>= 1) {
    s1 += __shfl_xor(s1, o);
    s2 += __shfl_xor(s2, o);
  }
  const float mu = s1 * (1.0f / CC);
  const float var = s2 * (1.0f / CC) - mu * mu;
  const float rs = 1.0f / sqrtf(var + 1e-5f);
  const float4 gg = ((const float4*)g)[lane];
  const float4 bb = ((const float4*)b)[lane];
  float4 o4;
  o4.x = (v.x - mu) * rs * gg.x + bb.x;
  o4.y = (v.y - mu) * rs * gg.y + bb.y;
  o4.z = (v.z - mu) * rs * gg.z + bb.z;
  o4.w = (v.w - mu) * rs * gg.w + bb.w;
  ((float4*)(out + (size_t)row * CC))[lane] = o4;
}

// LayerNorm -> split bf16 [hi(256) | lo(256)] per row (LN2 feeding MFMA MLP1).
__global__ __launch_bounds__(256) void ln_split(const float* __restrict__ x,
    const float* __restrict__ g, const float* __restrict__ b,
    u16* __restrict__ out) {
  const int wave = threadIdx.x >> 6, lane = threadIdx.x & 63;
  const int row = (blockIdx.x << 2) + wave;
  const float4 v = ((const float4*)(x + (size_t)row * CC))[lane];
  float s1 = v.x + v.y + v.z + v.w;
  float s2 = v.x * v.x + v.y * v.y + v.z * v.z + v.w * v.w;
#pragma unroll
  for (int o = 32; o > 0; o >>= 1) {
    s1 += __shfl_xor(s1, o);
    s2 += __shfl_xor(s2, o);
  }
  const float mu = s1 * (1.0f / CC);
  const float var = s2 * (1.0f / CC) - mu * mu;
  const float rs = 1.0f / sqrtf(var + 1e-5f);
  const float4 gg = ((const float4*)g)[lane];
  const float4 bb = ((const float4*)b)[lane];
  float o4[4];
  o4[0] = (v.x - mu) * rs * gg.x + bb.x;
  o4[1] = (v.y - mu) * rs * gg.y + bb.y;
  o4[2] = (v.z - mu) * rs * gg.z + bb.z;
  o4[3] = (v.w - mu) * rs * gg.w + bb.w;
  ushort4 hi, lo;
  hi.x = f2bf(o4[0]); lo.x = f2bf(o4[0] - bf2f(hi.x));
  hi.y = f2bf(o4[1]); lo.y = f2bf(o4[1] - bf2f(hi.y));
  hi.z = f2bf(o4[2]); lo.z = f2bf(o4[2] - bf2f(hi.z));
  hi.w = f2bf(o4[3]); lo.w = f2bf(o4[3] - bf2f(hi.w));
  *(ushort4*)(out + (size_t)row * 512 + (lane << 2)) = hi;
  *(ushort4*)(out + (size_t)row * 512 + 256 + (lane << 2)) = lo;
}

// ---------------------------------------------------------------------------
// fp32 VALU GEMM (round-1 proven; used for QKV so spike decisions match).
__global__ __launch_bounds__(256) void gemm_f32(const float* __restrict__ A,
    const float* __restrict__ W, const float* __restrict__ resid,
    float* __restrict__ Y, int K, int O) {
  __shared__ float As[16][68];
  __shared__ float Ws[16][68];
  const int tid = threadIdx.x;
  const int tx = tid & 15, ty = tid >> 4;
  const int r0 = blockIdx.y << 6, o0 = blockIdx.x << 6;
  const int lrow = tid >> 2, lk4 = (tid & 3) << 2;
  const float* Ap = A + (size_t)(r0 + lrow) * K + lk4;
  const float* Wp = W + (size_t)(o0 + lrow) * K + lk4;
  float acc[4][4] = {};
  for (int k0 = 0; k0 < K; k0 += 16) {
    const float4 a = *(const float4*)(Ap + k0);
    const float4 w = *(const float4*)(Wp + k0);
    __syncthreads();
    As[lk4 + 0][lrow] = a.x; As[lk4 + 1][lrow] = a.y;
    As[lk4 + 2][lrow] = a.z; As[lk4 + 3][lrow] = a.w;
    Ws[lk4 + 0][lrow] = w.x; Ws[lk4 + 1][lrow] = w.y;
    Ws[lk4 + 2][lrow] = w.z; Ws[lk4 + 3][lrow] = w.w;
    __syncthreads();
#pragma unroll
    for (int kk = 0; kk < 16; ++kk) {
      const float4 av = *(const float4*)&As[kk][ty << 2];
      const float4 wv = *(const float4*)&Ws[kk][tx << 2];
      acc[0][0] += av.x * wv.x; acc[0][1] += av.x * wv.y;
      acc[0][2] += av.x * wv.z; acc[0][3] += av.x * wv.w;
      acc[1][0] += av.y * wv.x; acc[1][1] += av.y * wv.y;
      acc[1][2] += av.y * wv.z; acc[1][3] += av.y * wv.w;
      acc[2][0] += av.z * wv.x; acc[2][1] += av.z * wv.y;
      acc[2][2] += av.z * wv.z; acc[2][3] += av.z * wv.w;
      acc[3][0] += av.w * wv.x; acc[3][1] += av.w * wv.y;
      acc[3][2] += av.w * wv.z; acc[3][3] += av.w * wv.w;
    }
  }
#pragma unroll
  for (int i = 0; i < 4; ++i) {
    const size_t idx = (size_t)(r0 + (ty << 2) + i) * O + o0 + (tx << 2);
    float4 v = make_float4(acc[i][0], acc[i][1], acc[i][2], acc[i][3]);
    if (resid) {
      const float4 rr = *(const float4*)(resid + idx);
      v.x += rr.x; v.y += rr.y; v.z += rr.z; v.w += rr.w;
    }
    *(float4*)(Y + idx) = v;
  }
}

// ---------------------------------------------------------------------------
// Weight splits into bf16 terms, K-concatenated.
// four=1: W2[o] = [W1 | W1 | W2 | W2] (width 4K)   pairs A=[hi|lo] (AW=2K)
// four=0: W2[o] = [W1 | W2]           (width 2K)   pairs exact-bf16 A (AW=K)
__global__ __launch_bounds__(256) void split_w(const float* __restrict__ W,
    u16* __restrict__ W2, int kmask, int logk, int four) {
  const int i = blockIdx.x * 256 + threadIdx.x;
  const int o = i >> logk, k = i & kmask;
  const int K = kmask + 1;
  const float w = W[i];
  const u16 hi = f2bf(w);
  const u16 lo = f2bf(w - bf2f(hi));
  if (four) {
    u16* base = W2 + (size_t)o * (K * 4);
    base[k] = hi; base[K + k] = hi; base[2 * K + k] = lo; base[3 * K + k] = lo;
  } else {
    u16* base = W2 + (size_t)o * (K * 2);
    base[k] = hi; base[K + k] = lo;
  }
}

// 3-term split for wo (256x256): W2[o] = [W1W1W1 | W2W2W2 | W3W3W3] width 2304,
// pairing A=[o1|o2|o3] (AW=768) cyclically -> all 9 products.
__global__ __launch_bounds__(256) void split_w3(const float* __restrict__ W,
    u16* __restrict__ W2) {
  const int i = blockIdx.x * 256 + threadIdx.x;
  const int o = i >> 8, k = i & 255;
  const float w = W[i];
  const u16 h1 = f2bf(w);
  const float r1 = w - bf2f(h1);
  const u16 h2 = f2bf(r1);
  const u16 h3 = f2bf(r1 - bf2f(h2));
  u16* base = W2 + (size_t)o * 2304;
  base[k] = h1;        base[256 + k] = h1;  base[512 + k] = h1;
  base[768 + k] = h2;  base[1024 + k] = h2; base[1280 + k] = h2;
  base[1536 + k] = h3; base[1792 + k] = h3; base[2048 + k] = h3;
}

// ---------------------------------------------------------------------------
// MFMA GEMM: Y[r,o] = sum_{k'} A[r, k' mod AW] * W2[o, k']  (+resid)
// 128x128 tile, BK=64, 4 waves (2x2), mfma_f32_16x16x32_bf16, global_load_lds.
__global__ __launch_bounds__(256) void gemm_mfma(
    const u16* __restrict__ A, int AW,
    const u16* __restrict__ W2, int K2,
    const float* __restrict__ resid, float* __restrict__ Y, int O) {
  __shared__ __align__(16) u16 As[128 * 64];
  __shared__ __align__(16) u16 Bs[128 * 64];
  const int tid = threadIdx.x;
  const int lane = tid & 63, wid = tid >> 6;
  const int wr = wid >> 1, wc = wid & 1;
  const int r0 = blockIdx.y << 7, o0 = blockIdx.x << 7;
  const int lrow = tid >> 3;          // 0..31
  const int lce = (tid & 7) << 3;     // 0,8,...,56
  float4v acc[4][4] = {};
  int kA = 0;
  for (int k0 = 0; k0 < K2; k0 += 64) {
#pragma unroll
    for (int i = 0; i < 4; ++i) {
      const u16* srcA = A + (size_t)(r0 + i * 32 + lrow) * AW + kA + lce;
      __builtin_amdgcn_global_load_lds(
          (const __attribute__((address_space(1))) void*)srcA,
          (__attribute__((address_space(3))) void*)&As[(i * 256 + (wid << 6)) << 3],
          16, 0, 0);
    }
#pragma unroll
    for (int i = 0; i < 4; ++i) {
      const u16* srcB = W2 + (size_t)(o0 + i * 32 + lrow) * K2 + k0 + lce;
      __builtin_amdgcn_global_load_lds(
          (const __attribute__((address_space(1))) void*)srcB,
          (__attribute__((address_space(3))) void*)&Bs[(i * 256 + (wid << 6)) << 3],
          16, 0, 0);
    }
    __syncthreads();
#pragma unroll
    for (int kk = 0; kk < 2; ++kk) {
      short8v a[4], b[4];
#pragma unroll
      for (int m = 0; m < 4; ++m)
        a[m] = *(const short8v*)&As[((wr << 6) + (m << 4) + (lane & 15)) * 64 +
                                    (kk << 5) + ((lane >> 4) << 3)];
#pragma unroll
      for (int n = 0; n < 4; ++n)
        b[n] = *(const short8v*)&Bs[((wc << 6) + (n << 4) + (lane & 15)) * 64 +
                                    (kk << 5) + ((lane >> 4) << 3)];
#pragma unroll
      for (int m = 0; m < 4; ++m)
#pragma unroll
        for (int n = 0; n < 4; ++n)
          acc[m][n] = __builtin_amdgcn_mfma_f32_16x16x32_bf16(a[m], b[n], acc[m][n], 0, 0, 0);
    }
    __syncthreads();
    kA += 64;
    if (kA >= AW) kA = 0;
  }
  const int crow = (lane >> 4) << 2, ccol = lane & 15;
#pragma unroll
  for (int m = 0; m < 4; ++m)
#pragma unroll
    for (int n = 0; n < 4; ++n)
#pragma unroll
      for (int j = 0; j < 4; ++j) {
        const size_t idx =
            (size_t)(r0 + (wr << 6) + (m << 4) + crow + j) * O +
            o0 + (wc << 6) + (n << 4) + ccol;
        float v = acc[m][n][j];
        if (resid) v += resid[idx];
        Y[idx] = v;
      }
}

// ---------------------------------------------------------------------------
// BatchNorm stats pass 1: per-block partial sum / sumsq per channel.
template <int O>
__global__ __launch_bounds__(256) void bn_stats1(const float* __restrict__ Y,
    float* __restrict__ p1, float* __restrict__ p2) {
  const int t = threadIdx.x;
  const int r0 = blockIdx.x << 6;
  constexpr int NCH = O / 256;
  float s1[NCH] = {}, s2[NCH] = {};
  for (int r = r0; r < r0 + 64; ++r) {
    const float* row = Y + (size_t)r * O;
#pragma unroll
    for (int c = 0; c < NCH; ++c) {
      const float y = row[t + (c << 8)];
      s1[c] += y;
      s2[c] += y * y;
    }
  }
#pragma unroll
  for (int c = 0; c < NCH; ++c) {
    p1[(size_t)blockIdx.x * O + t + (c << 8)] = s1[c];
    p2[(size_t)blockIdx.x * O + t + (c << 8)] = s2[c];
  }
}

__global__ __launch_bounds__(256) void bn_stats2(const float* __restrict__ p1,
    const float* __restrict__ p2, float* __restrict__ mu,
    float* __restrict__ rinv, int O) {
  const int o = blockIdx.x * 256 + threadIdx.x;
  float s1 = 0.f, s2 = 0.f;
  for (int j = 0; j < 256; ++j) {
    s1 += p1[(size_t)j * O + o];
    s2 += p2[(size_t)j * O + o];
  }
  const float m = s1 * (1.0f / 16384.f);
  const float v = s2 * (1.0f / 16384.f) - m * m;
  mu[o] = m;
  rinv[o] = 1.0f / sqrtf(v + 1e-5f);
}

// BN affine + Heaviside spike -> bf16 spikes {0, 0x3F80}.
__global__ __launch_bounds__(256) void bn_spike_bf16(const float* __restrict__ Y,
    const float* __restrict__ mu, const float* __restrict__ rinv,
    const float* __restrict__ g, const float* __restrict__ b,
    u16* __restrict__ S, int O) {
  const int i = blockIdx.x * 256 + threadIdx.x;
  const int c = (i << 2) & (O - 1);
  const float4 y = ((const float4*)Y)[i];
  const float4 m4 = *(const float4*)(mu + c);
  const float4 r4 = *(const float4*)(rinv + c);
  const float4 g4 = *(const float4*)(g + c);
  const float4 b4 = *(const float4*)(b + c);
  ushort4 s;
  s.x = ((y.x - m4.x) * r4.x * g4.x + b4.x >= 1.0f) ? (u16)0x3F80 : (u16)0;
  s.y = ((y.y - m4.y) * r4.y * g4.y + b4.y >= 1.0f) ? (u16)0x3F80 : (u16)0;
  s.z = ((y.z - m4.z) * r4.z * g4.z + b4.z >= 1.0f) ? (u16)0x3F80 : (u16)0;
  s.w = ((y.w - m4.w) * r4.w * g4.w + b4.w >= 1.0f) ? (u16)0x3F80 : (u16)0;
  ((ushort4*)S)[i] = s;
}

// BN affine + spike added into fp32 output (final residual).
__global__ __launch_bounds__(256) void bn_spike_add(const float* __restrict__ Y,
    const float* __restrict__ mu, const float* __restrict__ rinv,
    const float* __restrict__ g, const float* __restrict__ b,
    float* __restrict__ addOut, int O) {
  const int i = blockIdx.x * 256 + threadIdx.x;
  const int c = (i << 2) & (O - 1);
  const float4 y = ((const float4*)Y)[i];
  const float4 m4 = *(const float4*)(mu + c);
  const float4 r4 = *(const float4*)(rinv + c);
  const float4 g4 = *(const float4*)(g + c);
  const float4 b4 = *(const float4*)(b + c);
  float4 o4 = ((const float4*)addOut)[i];
  o4.x += ((y.x - m4.x) * r4.x * g4.x + b4.x >= 1.0f) ? 1.0f : 0.0f;
  o4.y += ((y.y - m4.y) * r4.y * g4.y + b4.y >= 1.0f) ? 1.0f : 0.0f;
  o4.z += ((y.z - m4.z) * r4.z * g4.z + b4.z >= 1.0f) ? 1.0f : 0.0f;
  o4.w += ((y.w - m4.w) * r4.w * g4.w + b4.w >= 1.0f) ? 1.0f : 0.0f;
  ((float4*)addOut)[i] = o4;
}

// ---------------------------------------------------------------------------
// M[b,h] = K^T V (64x64), split over n into 8 partials. Inputs: bf16 spikes.
__global__ __launch_bounds__(256) void attn_kv(const u16* __restrict__ Ksp,
    const u16* __restrict__ Vsp, float* __restrict__ Mpart) {
  const int bh = blockIdx.x, sp = blockIdx.y;
  const int b = bh >> 2, h = bh & 3;
  const int t = threadIdx.x;
  const int gq = t >> 6, e = t & 63;
  const size_t base = (size_t)b * NN * CC + (h << 6);
  __shared__ float ks[16][64], vs[16][64];
  float acc[16] = {};
  const int lrow = t >> 4, lf = (t & 15) << 2;
  for (int n0 = sp * 256; n0 < sp * 256 + 256; n0 += 16) {
    const ushort4 kq = *(const ushort4*)(Ksp + base + (size_t)(n0 + lrow) * CC + lf);
    const ushort4 vq = *(const ushort4*)(Vsp + base + (size_t)(n0 + lrow) * CC + lf);
    __syncthreads();
    ks[lrow][lf + 0] = bf2f(kq.x); ks[lrow][lf + 1] = bf2f(kq.y);
    ks[lrow][lf + 2] = bf2f(kq.z); ks[lrow][lf + 3] = bf2f(kq.w);
    vs[lrow][lf + 0] = bf2f(vq.x); vs[lrow][lf + 1] = bf2f(vq.y);
    vs[lrow][lf + 2] = bf2f(vq.z); vs[lrow][lf + 3] = bf2f(vq.w);
    __syncthreads();
#pragma unroll
    for (int nn = 0; nn < 16; ++nn) {
      const float vv = vs[nn][e];
#pragma unroll
      for (int i = 0; i < 16; ++i) acc[i] += ks[nn][(gq << 4) + i] * vv;
    }
  }
  float* mp = Mpart + (((size_t)bh << 3) + sp) * 4096;
#pragma unroll
  for (int i = 0; i < 16; ++i) mp[((gq << 4) + i) * 64 + e] = acc[i];
}

__global__ __launch_bounds__(256) void attn_kv_reduce(
    const float* __restrict__ Mpart, float* __restrict__ M) {
  const int i = blockIdx.x * 256 + threadIdx.x;
  const int bh = i >> 12, j = i & 4095;
  float s = 0.f;
#pragma unroll
  for (int sp = 0; sp < 8; ++sp)
    s += Mpart[(((size_t)((bh << 3) + sp)) << 12) + j];
  M[i] = s;
}

// o = 0.125 * q @ M (exact), written as EXACT 3-term bf16 [o1|o2|o3] (w=768).
__global__ __launch_bounds__(256) void attn_qm(const u16* __restrict__ Qsp,
    const float* __restrict__ M, u16* __restrict__ O3) {
  const int h = blockIdx.x;
  const int r0 = blockIdx.y << 6;
  const int b = blockIdx.y >> 5;
  const int t = threadIdx.x;
  const int e = t & 63, rg = t >> 6;
  __shared__ float Ms[64][64];
  __shared__ float qs[64][64];
  const float* Mb = M + ((size_t)(b * 4 + h) << 12);
  for (int i = t; i < 4096; i += 256) ((float*)Ms)[i] = Mb[i];
  for (int rl = rg; rl < 64; rl += 4)
    qs[rl][e] = bf2f(Qsp[(size_t)(r0 + rl) * CC + (h << 6) + e]);
  __syncthreads();
  for (int rl = rg; rl < 64; rl += 4) {
    float acc = 0.f;
#pragma unroll
    for (int d = 0; d < 64; ++d) acc += qs[rl][d] * Ms[d][e];
    const float o = 0.125f * acc;
    const u16 a = f2bf(o);
    const float r1 = o - bf2f(a);
    const u16 b2 = f2bf(r1);
    const u16 c = f2bf(r1 - bf2f(b2));
    u16* row = O3 + (size_t)(r0 + rl) * 768 + (h << 6) + e;
    row[0] = a; row[256] = b2; row[512] = c;
  }
}

// ---------------------------------------------------------------------------
extern "C" void kernel_launch(void* const* d_in, const int* in_sizes, int n_in,
                              void* d_out, int out_size, void* d_ws,
                              size_t ws_size, hipStream_t stream) {
  const float* x    = (const float*)d_in[0];
  const float* ln1g = (const float*)d_in[1];
  const float* ln1b = (const float*)d_in[2];
  const float* wq   = (const float*)d_in[3];
  const float* qg   = (const float*)d_in[4];
  const float* qb   = (const float*)d_in[5];
  const float* wk   = (const float*)d_in[6];
  const float* kg   = (const float*)d_in[7];
  const float* kb   = (const float*)d_in[8];
  const float* wv   = (const float*)d_in[9];
  const float* vg   = (const float*)d_in[10];
  const float* vb   = (const float*)d_in[11];
  const float* wo   = (const float*)d_in[12];
  const float* ln2g = (const float*)d_in[13];
  const float* ln2b = (const float*)d_in[14];
  const float* w1   = (const float*)d_in[15];
  const float* b1g  = (const float*)d_in[16];
  const float* b1b  = (const float*)d_in[17];
  const float* w2   = (const float*)d_in[18];
  const float* b2g  = (const float*)d_in[19];
  const float* b2b  = (const float*)d_in[20];
  float* out = (float*)d_out;
  char* ws = (char*)d_ws;
  const size_t MB = 1u << 20;
  // Arena (max 144 MB), phase-overlaid:
  float* A     = (float*)(ws);             // [0,16)   h1 fp32 (dead after QKV)
  float* Yq    = (float*)(ws + 16 * MB);   // [16,32)  QKV pre-BN fp32
  u16*   qs_   = (u16*)(ws + 32 * MB);     // [32,40)
  u16*   ks_   = (u16*)(ws + 40 * MB);     // [40,48)
  u16*   vs_   = (u16*)(ws + 48 * MB);     // [48,56)
  float* Mpart = (float*)(ws + 56 * MB);   // [56,60)
  float* Mful  = (float*)(ws + 60 * MB);   // [60,60.5)
  u16*   o3    = (u16*)(ws);               // [0,24)   overlays A+low Yq (dead)
  u16*   h2s   = (u16*)(ws + 24 * MB);     // [24,40)  overlays hi Yq+qs (dead)
  float* Ym    = (float*)(ws + 40 * MB);   // [40,104) MLP1 out; MLP2 reuses low 16
  u16*   m1    = (u16*)(ws + 104 * MB);    // [104,136)
  u16*   wo2   = (u16*)(ws + 136 * MB);    // 256x2304 bf16 = 1.125 MB
  u16*   w12   = (u16*)(ws + 138 * MB);    // 1024x1024 bf16 = 2 MB
  u16*   w22   = (u16*)(ws + 140 * MB);    // 256x2048 bf16 = 1 MB
  float* p1    = (float*)(ws + 141 * MB);
  float* p2    = (float*)(ws + 142 * MB);
  float* mu    = (float*)(ws + 143 * MB);
  float* rinv  = (float*)(ws + 143 * MB + 32768);

  const dim3 blk(256);

  // Weight splits (wo 3-term; w1 2x2; w2 binary-A x 2-term)
  split_w3<<<256, blk, 0, stream>>>(wo, wo2);
  split_w<<<1024, blk, 0, stream>>>(w1, w12, 255, 8, 1);
  split_w<<<1024, blk, 0, stream>>>(w2, w22, 1023, 10, 0);

  // 1. h1 = LN1(x) fp32
  ln_kernel<<<RR / 4, blk, 0, stream>>>(x, ln1g, ln1b, A);

  // 2-3. QKV projections (fp32 VALU, proven accuracy) + BN + spike -> bf16
  {
    const float* Wt[3] = {wq, wk, wv};
    const float* gs[3] = {qg, kg, vg};
    const float* bs[3] = {qb, kb, vb};
    u16* Ss[3] = {qs_, ks_, vs_};
    for (int i = 0; i < 3; ++i) {
      gemm_f32<<<dim3(4, 256), blk, 0, stream>>>(A, Wt[i], nullptr, Yq, 256, 256);
      bn_stats1<256><<<256, blk, 0, stream>>>(Yq, p1, p2);
      bn_stats2<<<1, blk, 0, stream>>>(p1, p2, mu, rinv, 256);
      bn_spike_bf16<<<4096, blk, 0, stream>>>(Yq, mu, rinv, gs[i], bs[i],
                                              Ss[i], 256);
    }
  }

  // 4-6. attention: M = K^T V (exact int), o = 0.125 q@M -> exact 3-term split
  attn_kv<<<dim3(32, 8), blk, 0, stream>>>(ks_, vs_, Mpart);
  attn_kv_reduce<<<512, blk, 0, stream>>>(Mpart, Mful);
  attn_qm<<<dim3(4, RR / 64), blk, 0, stream>>>(qs_, Mful, o3);

  // 7. x2 = x + o @ wo^T -> out   (MFMA, 3x3 split, K'=2304)
  gemm_mfma<<<dim3(2, 128), blk, 0, stream>>>(o3, 768, wo2, 2304, x, out, 256);

  // 8. h2 = LN2(x2) -> split bf16
  ln_split<<<RR / 4, blk, 0, stream>>>(out, ln2g, ln2b, h2s);

  // 9-10. MLP1 (MFMA 2x2 split, K'=1024) + BN + spike -> m1
  gemm_mfma<<<dim3(8, 128), blk, 0, stream>>>(h2s, 512, w12, 1024, nullptr,
                                              Ym, 1024);
  bn_stats1<1024><<<256, blk, 0, stream>>>(Ym, p1, p2);
  bn_stats2<<<4, blk, 0, stream>>>(p1, p2, mu, rinv, 1024);
  bn_spike_bf16<<<16384, blk, 0, stream>>>(Ym, mu, rinv, b1g, b1b, m1, 1024);

  // 11-12. MLP2 (MFMA, binary-exact A x 2-term W, K'=2048) + BN + spike-add
  gemm_mfma<<<dim3(2, 128), blk, 0, stream>>>(m1, 1024, w22, 2048, nullptr,
                                              Ym, 256);
  bn_stats1<256><<<256, blk, 0, stream>>>(Ym, p1, p2);
  bn_stats2<<<1, blk, 0, stream>>>(p1, p2, mu, rinv, 256);
  bn_spike_add<<<4096, blk, 0, stream>>>(Ym, mu, rinv, b2g, b2b, out, 256);
}

// Round 4
// 367.652 us; speedup vs baseline: 1.7686x; 1.4892x over previous
//
#include <hip/hip_runtime.h>
#include <cstddef>
#include <cstdint>

#define RR 16384   // B*N rows
#define CC 256
#define NN 2048

typedef __attribute__((ext_vector_type(8))) _Float16 h8;
typedef __attribute__((ext_vector_type(4))) float float4v;
typedef unsigned short u16;

__device__ inline float h2f(u16 u) {
  return (float)__builtin_bit_cast(_Float16, u);
}
__device__ inline u16 f2h(float f) {
  return __builtin_bit_cast(u16, (_Float16)f);
}

// ---------------------------------------------------------------------------
// LayerNorm -> split f16 [hi(256) | lo(256)] per row.
__global__ __launch_bounds__(256) void ln_split(const float* __restrict__ x,
    const float* __restrict__ g, const float* __restrict__ b,
    u16* __restrict__ out) {
  const int wave = threadIdx.x >> 6, lane = threadIdx.x & 63;
  const int row = (blockIdx.x << 2) + wave;
  const float4 v = ((const float4*)(x + (size_t)row * CC))[lane];
  float s1 = v.x + v.y + v.z + v.w;
  float s2 = v.x * v.x + v.y * v.y + v.z * v.z + v.w * v.w;
#pragma unroll
  for (int o = 32; o > 0; o >>= 1) {
    s1 += __shfl_xor(s1, o);
    s2 += __shfl_xor(s2, o);
  }
  const float mu = s1 * (1.0f / CC);
  const float var = s2 * (1.0f / CC) - mu * mu;
  const float rs = 1.0f / sqrtf(var + 1e-5f);
  const float4 gg = ((const float4*)g)[lane];
  const float4 bb = ((const float4*)b)[lane];
  float o4[4];
  o4[0] = (v.x - mu) * rs * gg.x + bb.x;
  o4[1] = (v.y - mu) * rs * gg.y + bb.y;
  o4[2] = (v.z - mu) * rs * gg.z + bb.z;
  o4[3] = (v.w - mu) * rs * gg.w + bb.w;
  ushort4 hi, lo;
  hi.x = f2h(o4[0]); lo.x = f2h(o4[0] - h2f(hi.x));
  hi.y = f2h(o4[1]); lo.y = f2h(o4[1] - h2f(hi.y));
  hi.z = f2h(o4[2]); lo.z = f2h(o4[2] - h2f(hi.z));
  hi.w = f2h(o4[3]); lo.w = f2h(o4[3] - h2f(hi.w));
  *(ushort4*)(out + (size_t)row * 512 + (lane << 2)) = hi;
  *(ushort4*)(out + (size_t)row * 512 + 256 + (lane << 2)) = lo;
}

// ---------------------------------------------------------------------------
// Weight splits to f16 2-term, K-concatenated.
// [W1|W1|W2|W2] width 4K (K=256) at row offset rowoff: pairs A=[hi|lo] (AW=2K)
__global__ __launch_bounds__(256) void split_wf4(const float* __restrict__ W,
    u16* __restrict__ W2, int rowoff) {
  const int i = blockIdx.x * 256 + threadIdx.x;
  const int o = i >> 8, k = i & 255;
  const float w = W[i];
  const u16 h1 = f2h(w);
  const u16 h2 = f2h(w - h2f(h1));
  u16* base = W2 + (size_t)(o + rowoff) * 1024;
  base[k] = h1; base[256 + k] = h1; base[512 + k] = h2; base[768 + k] = h2;
}

// [W1|W2] width 2K (K=1024): pairs exact-f16 A (AW=K)
__global__ __launch_bounds__(256) void split_wf2(const float* __restrict__ W,
    u16* __restrict__ W2) {
  const int i = blockIdx.x * 256 + threadIdx.x;
  const int o = i >> 10, k = i & 1023;
  const float w = W[i];
  const u16 h1 = f2h(w);
  const u16 h2 = f2h(w - h2f(h1));
  u16* base = W2 + (size_t)o * 2048;
  base[k] = h1; base[1024 + k] = h2;
}

// ---------------------------------------------------------------------------
// MFMA f16 GEMM: Y[r,o] = sum_{k'} A[r, k' mod AW] * W2[o, k']  (+resid)
// Tile BM x BN, BK=64, 4 waves (WMxWN), mfma_f32_16x16x32_f16.
// T2 LDS swizzle both-sides: source chunk ^= (row&7), ds_read chunk ^= (row&7).
template <int BM, int BN, int WM, int WN>
__global__ __launch_bounds__(256) void gemm_sp(
    const u16* __restrict__ A, int AW,
    const u16* __restrict__ W2, int K2,
    const float* __restrict__ resid, float* __restrict__ Y, int O) {
  constexpr int FM = BM / (WM * 16);
  constexpr int FN = BN / (WN * 16);
  __shared__ __align__(16) u16 As[BM * 64];
  __shared__ __align__(16) u16 Bs[BN * 64];
  const int tid = threadIdx.x;
  const int lane = tid & 63, wid = tid >> 6;
  const int wr = wid / WN, wc = wid % WN;
  const int r0 = blockIdx.y * BM, o0 = blockIdx.x * BN;
  const int lrow = tid >> 3;                             // 0..31
  const int lce = ((tid & 7) ^ ((tid >> 3) & 7)) << 3;   // swizzled src chunk
  float4v acc[FM][FN] = {};
  int kA = 0;
  for (int k0 = 0; k0 < K2; k0 += 64) {
#pragma unroll
    for (int i = 0; i < BM / 32; ++i) {
      const u16* srcA = A + (size_t)(r0 + i * 32 + lrow) * AW + kA + lce;
      __builtin_amdgcn_global_load_lds(
          (const __attribute__((address_space(1))) void*)srcA,
          (__attribute__((address_space(3))) void*)&As[(i * 256 + (wid << 6)) * 8],
          16, 0, 0);
    }
#pragma unroll
    for (int i = 0; i < BN / 32; ++i) {
      const u16* srcB = W2 + (size_t)(o0 + i * 32 + lrow) * K2 + k0 + lce;
      __builtin_amdgcn_global_load_lds(
          (const __attribute__((address_space(1))) void*)srcB,
          (__attribute__((address_space(3))) void*)&Bs[(i * 256 + (wid << 6)) * 8],
          16, 0, 0);
    }
    __syncthreads();
#pragma unroll
    for (int kk = 0; kk < 2; ++kk) {
      h8 a[FM], b[FN];
      const int ch0 = (kk << 2) + (lane >> 4);
      const int chs = ch0 ^ (lane & 7);   // row&7 == lane&7 for all fragments
#pragma unroll
      for (int m = 0; m < FM; ++m) {
        const int R = wr * (FM * 16) + m * 16 + (lane & 15);
        a[m] = *(const h8*)&As[R * 64 + chs * 8];
      }
#pragma unroll
      for (int n = 0; n < FN; ++n) {
        const int Rb = wc * (FN * 16) + n * 16 + (lane & 15);
        b[n] = *(const h8*)&Bs[Rb * 64 + chs * 8];
      }
#pragma unroll
      for (int m = 0; m < FM; ++m)
#pragma unroll
        for (int n = 0; n < FN; ++n)
          acc[m][n] = __builtin_amdgcn_mfma_f32_16x16x32_f16(a[m], b[n], acc[m][n], 0, 0, 0);
    }
    __syncthreads();
    kA += 64;
    if (kA >= AW) kA = 0;
  }
  const int crow = (lane >> 4) << 2, ccol = lane & 15;
#pragma unroll
  for (int m = 0; m < FM; ++m)
#pragma unroll
    for (int n = 0; n < FN; ++n)
#pragma unroll
      for (int j = 0; j < 4; ++j) {
        const size_t idx =
            (size_t)(r0 + wr * (FM * 16) + (m << 4) + crow + j) * O +
            o0 + wc * (FN * 16) + (n << 4) + ccol;
        float v = acc[m][n][j];
        if (resid) v += resid[idx];
        Y[idx] = v;
      }
}

// ---------------------------------------------------------------------------
// BatchNorm stats pass 1: per-block partial sum / sumsq per channel.
template <int O>
__global__ __launch_bounds__(256) void bn_stats1(const float* __restrict__ Y,
    float* __restrict__ p1, float* __restrict__ p2) {
  const int t = threadIdx.x;
  const int r0 = blockIdx.x << 6;
  constexpr int NCH = O / 256;
  float s1[NCH] = {}, s2[NCH] = {};
  for (int r = r0; r < r0 + 64; ++r) {
    const float* row = Y + (size_t)r * O;
#pragma unroll
    for (int c = 0; c < NCH; ++c) {
      const float y = row[t + (c << 8)];
      s1[c] += y;
      s2[c] += y * y;
    }
  }
#pragma unroll
  for (int c = 0; c < NCH; ++c) {
    p1[(size_t)blockIdx.x * O + t + (c << 8)] = s1[c];
    p2[(size_t)blockIdx.x * O + t + (c << 8)] = s2[c];
  }
}

__global__ __launch_bounds__(256) void bn_stats2(const float* __restrict__ p1,
    const float* __restrict__ p2, float* __restrict__ mu,
    float* __restrict__ rinv, int O) {
  const int o = blockIdx.x * 256 + threadIdx.x;
  float s1 = 0.f, s2 = 0.f;
  for (int j = 0; j < 256; ++j) {
    s1 += p1[(size_t)j * O + o];
    s2 += p2[(size_t)j * O + o];
  }
  const float m = s1 * (1.0f / 16384.f);
  const float v = s2 * (1.0f / 16384.f) - m * m;
  mu[o] = m;
  rinv[o] = 1.0f / sqrtf(v + 1e-5f);
}

// Fused QKV BN + spike: Yq is R x 768 = [q|k|v] channels; writes 3 spike bufs.
__global__ __launch_bounds__(256) void qkv_spike(const float* __restrict__ Yq,
    const float* __restrict__ mu, const float* __restrict__ rinv,
    const float* __restrict__ qg, const float* __restrict__ qb,
    const float* __restrict__ kg, const float* __restrict__ kb,
    const float* __restrict__ vg, const float* __restrict__ vb,
    u16* __restrict__ qs, u16* __restrict__ ks, u16* __restrict__ vs) {
  const int i = blockIdx.x * 256 + threadIdx.x;  // float4 id over R*192
  const int r = i / 192, c4 = i - r * 192;
  const int c = c4 << 2;
  const int sel = c >> 8, cc = c & 255;
  const float4 y = ((const float4*)Yq)[i];
  const float4 m4 = *(const float4*)(mu + c);
  const float4 r4 = *(const float4*)(rinv + c);
  const float* g = (sel == 0) ? qg : (sel == 1) ? kg : vg;
  const float* b = (sel == 0) ? qb : (sel == 1) ? kb : vb;
  const float4 g4 = *(const float4*)(g + cc);
  const float4 b4 = *(const float4*)(b + cc);
  ushort4 s;
  s.x = ((y.x - m4.x) * r4.x * g4.x + b4.x >= 1.0f) ? (u16)0x3C00 : (u16)0;
  s.y = ((y.y - m4.y) * r4.y * g4.y + b4.y >= 1.0f) ? (u16)0x3C00 : (u16)0;
  s.z = ((y.z - m4.z) * r4.z * g4.z + b4.z >= 1.0f) ? (u16)0x3C00 : (u16)0;
  s.w = ((y.w - m4.w) * r4.w * g4.w + b4.w >= 1.0f) ? (u16)0x3C00 : (u16)0;
  u16* dst = ((sel == 0) ? qs : (sel == 1) ? ks : vs) + (size_t)r * 256 + cc;
  *(ushort4*)dst = s;
}

// BN affine + Heaviside spike -> f16 spikes {0, 0x3C00}.
__global__ __launch_bounds__(256) void bn_spike_f16(const float* __restrict__ Y,
    const float* __restrict__ mu, const float* __restrict__ rinv,
    const float* __restrict__ g, const float* __restrict__ b,
    u16* __restrict__ S, int O) {
  const int i = blockIdx.x * 256 + threadIdx.x;
  const int c = (i << 2) & (O - 1);
  const float4 y = ((const float4*)Y)[i];
  const float4 m4 = *(const float4*)(mu + c);
  const float4 r4 = *(const float4*)(rinv + c);
  const float4 g4 = *(const float4*)(g + c);
  const float4 b4 = *(const float4*)(b + c);
  ushort4 s;
  s.x = ((y.x - m4.x) * r4.x * g4.x + b4.x >= 1.0f) ? (u16)0x3C00 : (u16)0;
  s.y = ((y.y - m4.y) * r4.y * g4.y + b4.y >= 1.0f) ? (u16)0x3C00 : (u16)0;
  s.z = ((y.z - m4.z) * r4.z * g4.z + b4.z >= 1.0f) ? (u16)0x3C00 : (u16)0;
  s.w = ((y.w - m4.w) * r4.w * g4.w + b4.w >= 1.0f) ? (u16)0x3C00 : (u16)0;
  ((ushort4*)S)[i] = s;
}

// BN affine + spike added into fp32 output (final residual).
__global__ __launch_bounds__(256) void bn_spike_add(const float* __restrict__ Y,
    const float* __restrict__ mu, const float* __restrict__ rinv,
    const float* __restrict__ g, const float* __restrict__ b,
    float* __restrict__ addOut, int O) {
  const int i = blockIdx.x * 256 + threadIdx.x;
  const int c = (i << 2) & (O - 1);
  const float4 y = ((const float4*)Y)[i];
  const float4 m4 = *(const float4*)(mu + c);
  const float4 r4 = *(const float4*)(rinv + c);
  const float4 g4 = *(const float4*)(g + c);
  const float4 b4 = *(const float4*)(b + c);
  float4 o4 = ((const float4*)addOut)[i];
  o4.x += ((y.x - m4.x) * r4.x * g4.x + b4.x >= 1.0f) ? 1.0f : 0.0f;
  o4.y += ((y.y - m4.y) * r4.y * g4.y + b4.y >= 1.0f) ? 1.0f : 0.0f;
  o4.z += ((y.z - m4.z) * r4.z * g4.z + b4.z >= 1.0f) ? 1.0f : 0.0f;
  o4.w += ((y.w - m4.w) * r4.w * g4.w + b4.w >= 1.0f) ? 1.0f : 0.0f;
  ((float4*)addOut)[i] = o4;
}

// ---------------------------------------------------------------------------
// M[b,h] = K^T V (64x64), split over n into 16 partials. Inputs: f16 spikes.
__global__ __launch_bounds__(256) void attn_kv(const u16* __restrict__ Ksp,
    const u16* __restrict__ Vsp, float* __restrict__ Mpart) {
  const int bh = blockIdx.x, sp = blockIdx.y;
  const int b = bh >> 2, h = bh & 3;
  const int t = threadIdx.x;
  const int gq = t >> 6, e = t & 63;
  const size_t base = (size_t)b * NN * CC + (h << 6);
  __shared__ float ks[16][64], vs[16][64];
  float acc[16] = {};
  const int lrow = t >> 4, lf = (t & 15) << 2;
  for (int n0 = sp * 128; n0 < sp * 128 + 128; n0 += 16) {
    const ushort4 kq = *(const ushort4*)(Ksp + base + (size_t)(n0 + lrow) * CC + lf);
    const ushort4 vq = *(const ushort4*)(Vsp + base + (size_t)(n0 + lrow) * CC + lf);
    __syncthreads();
    ks[lrow][lf + 0] = h2f(kq.x); ks[lrow][lf + 1] = h2f(kq.y);
    ks[lrow][lf + 2] = h2f(kq.z); ks[lrow][lf + 3] = h2f(kq.w);
    vs[lrow][lf + 0] = h2f(vq.x); vs[lrow][lf + 1] = h2f(vq.y);
    vs[lrow][lf + 2] = h2f(vq.z); vs[lrow][lf + 3] = h2f(vq.w);
    __syncthreads();
#pragma unroll
    for (int nn = 0; nn < 16; ++nn) {
      const float vv = vs[nn][e];
#pragma unroll
      for (int i = 0; i < 16; ++i) acc[i] += ks[nn][(gq << 4) + i] * vv;
    }
  }
  float* mp = Mpart + ((size_t)bh * 16 + sp) * 4096;
#pragma unroll
  for (int i = 0; i < 16; ++i) mp[((gq << 4) + i) * 64 + e] = acc[i];
}

__global__ __launch_bounds__(256) void attn_kv_reduce(
    const float* __restrict__ Mpart, float* __restrict__ M) {
  const int i = blockIdx.x * 256 + threadIdx.x;
  const int bh = i >> 12, j = i & 4095;
  float s = 0.f;
#pragma unroll
  for (int sp = 0; sp < 16; ++sp)
    s += Mpart[((size_t)bh * 16 + sp) * 4096 + j];
  M[i] = s;
}

// o = 0.125 * q @ M (exact), written as EXACT 2-term f16 [o1|o2] (width 512).
__global__ __launch_bounds__(256) void attn_qm(const u16* __restrict__ Qsp,
    const float* __restrict__ M, u16* __restrict__ O2) {
  const int h = blockIdx.x;
  const int r0 = blockIdx.y << 6;
  const int b = blockIdx.y >> 5;
  const int t = threadIdx.x;
  const int e = t & 63, rg = t >> 6;
  __shared__ float Ms[64][64];
  __shared__ float qs[64][64];
  const float* Mb = M + ((size_t)(b * 4 + h) << 12);
  for (int i = t; i < 4096; i += 256) ((float*)Ms)[i] = Mb[i];
  for (int rl = rg; rl < 64; rl += 4)
    qs[rl][e] = h2f(Qsp[(size_t)(r0 + rl) * CC + (h << 6) + e]);
  __syncthreads();
  for (int rl = rg; rl < 64; rl += 4) {
    float acc = 0.f;
#pragma unroll
    for (int d = 0; d < 64; ++d) acc += qs[rl][d] * Ms[d][e];
    const float o = 0.125f * acc;   // exact multiple of 1/8, |o| <= 16384
    const u16 hi = f2h(o);
    const u16 lo = f2h(o - h2f(hi));  // exact 2-term
    O2[(size_t)(r0 + rl) * 512 + (h << 6) + e] = hi;
    O2[(size_t)(r0 + rl) * 512 + 256 + (h << 6) + e] = lo;
  }
}

// ---------------------------------------------------------------------------
extern "C" void kernel_launch(void* const* d_in, const int* in_sizes, int n_in,
                              void* d_out, int out_size, void* d_ws,
                              size_t ws_size, hipStream_t stream) {
  const float* x    = (const float*)d_in[0];
  const float* ln1g = (const float*)d_in[1];
  const float* ln1b = (const float*)d_in[2];
  const float* wq   = (const float*)d_in[3];
  const float* qg   = (const float*)d_in[4];
  const float* qb   = (const float*)d_in[5];
  const float* wk   = (const float*)d_in[6];
  const float* kg   = (const float*)d_in[7];
  const float* kb   = (const float*)d_in[8];
  const float* wv   = (const float*)d_in[9];
  const float* vg   = (const float*)d_in[10];
  const float* vb   = (const float*)d_in[11];
  const float* wo   = (const float*)d_in[12];
  const float* ln2g = (const float*)d_in[13];
  const float* ln2b = (const float*)d_in[14];
  const float* w1   = (const float*)d_in[15];
  const float* b1g  = (const float*)d_in[16];
  const float* b1b  = (const float*)d_in[17];
  const float* w2   = (const float*)d_in[18];
  const float* b2g  = (const float*)d_in[19];
  const float* b2b  = (const float*)d_in[20];
  float* out = (float*)d_out;
  char* ws = (char*)d_ws;
  const size_t MB = 1u << 20;
  // Arena (<=137 MB), phase-overlaid:
  u16*   h1s   = (u16*)(ws);               // [0,16)   dead after QKV gemm
  float* Yq    = (float*)(ws + 16 * MB);   // [16,64)  R x 768 fp32
  u16*   qs_   = (u16*)(ws + 64 * MB);     // [64,72)
  u16*   ks_   = (u16*)(ws + 72 * MB);     // [72,80)
  u16*   vs_   = (u16*)(ws + 80 * MB);     // [80,88)
  float* Mpart = (float*)(ws + 88 * MB);   // [88,96)  8 MB
  float* Mful  = (float*)(ws + 96 * MB);   // [96,96.5)
  u16*   o2    = (u16*)(ws);               // [0,16)   overlays h1s (dead)
  u16*   h2s   = (u16*)(ws + 16 * MB);     // [16,32)  overlays Yq-lo (dead)
  float* Ym    = (float*)(ws + 32 * MB);   // [32,96)  R x 1024 fp32 (MLP)
  u16*   m1    = (u16*)(ws + 97 * MB);     // [97,129) R x 1024 f16
  u16*   Wqkv  = (u16*)(ws + 129 * MB);    // 768 x 1024 f16 = 1.5 MB
  u16*   wo2   = (u16*)(ws + 131 * MB);    // 256 x 1024 f16 = 0.5 MB
  u16*   w12   = (u16*)(ws + 132 * MB);    // 1024 x 1024 f16 = 2 MB
  u16*   w22   = (u16*)(ws + 134 * MB);    // 256 x 2048 f16 = 1 MB
  float* p1    = (float*)(ws + 135 * MB);  // 256 x 1024 = 1 MB
  float* p2    = (float*)(ws + 136 * MB);  // 1 MB
  float* mu    = (float*)(ws + 137 * MB);
  float* rinv  = (float*)(ws + 137 * MB + 32768);

  const dim3 blk(256);

  // Weight splits (f16 2-term)
  split_wf4<<<256,  blk, 0, stream>>>(wq, Wqkv, 0);
  split_wf4<<<256,  blk, 0, stream>>>(wk, Wqkv, 256);
  split_wf4<<<256,  blk, 0, stream>>>(wv, Wqkv, 512);
  split_wf4<<<256,  blk, 0, stream>>>(wo, wo2, 0);
  split_wf4<<<1024, blk, 0, stream>>>(w1, w12, 0);
  split_wf2<<<1024, blk, 0, stream>>>(w2, w22);

  // 1. h1 = LN1(x) -> split f16
  ln_split<<<RR / 4, blk, 0, stream>>>(x, ln1g, ln1b, h1s);

  // 2. Fused QKV projection (MFMA, O=768, grid 768 blocks)
  gemm_sp<128, 128, 2, 2><<<dim3(6, 128), blk, 0, stream>>>(
      h1s, 512, Wqkv, 1024, nullptr, Yq, 768);

  // 3. BN stats + spike for q|k|v
  bn_stats1<768><<<256, blk, 0, stream>>>(Yq, p1, p2);
  bn_stats2<<<3, blk, 0, stream>>>(p1, p2, mu, rinv, 768);
  qkv_spike<<<RR * 192 / 256, blk, 0, stream>>>(Yq, mu, rinv, qg, qb, kg, kb,
                                                vg, vb, qs_, ks_, vs_);

  // 4-6. attention: M = K^T V (exact int), o = 0.125 q@M -> exact 2-term f16
  attn_kv<<<dim3(32, 16), blk, 0, stream>>>(ks_, vs_, Mpart);
  attn_kv_reduce<<<512, blk, 0, stream>>>(Mpart, Mful);
  attn_qm<<<dim3(4, RR / 64), blk, 0, stream>>>(qs_, Mful, o2);

  // 7. x2 = x + o @ wo^T -> out   (MFMA, exact-A x 2-term W, K'=1024)
  gemm_sp<64, 128, 2, 2><<<dim3(2, 256), blk, 0, stream>>>(
      o2, 512, wo2, 1024, x, out, 256);

  // 8. h2 = LN2(x2) -> split f16
  ln_split<<<RR / 4, blk, 0, stream>>>(out, ln2g, ln2b, h2s);

  // 9-10. MLP1 (2x2 f16 split, K'=1024) + BN + spike -> m1
  gemm_sp<128, 128, 2, 2><<<dim3(8, 128), blk, 0, stream>>>(
      h2s, 512, w12, 1024, nullptr, Ym, 1024);
  bn_stats1<1024><<<256, blk, 0, stream>>>(Ym, p1, p2);
  bn_stats2<<<4, blk, 0, stream>>>(p1, p2, mu, rinv, 1024);
  bn_spike_f16<<<16384, blk, 0, stream>>>(Ym, mu, rinv, b1g, b1b, m1, 1024);

  // 11-12. MLP2 (binary-exact A x 2-term W, K'=2048) + BN + spike-add
  gemm_sp<64, 128, 2, 2><<<dim3(2, 256), blk, 0, stream>>>(
      m1, 1024, w22, 2048, nullptr, Ym, 256);
  bn_stats1<256><<<256, blk, 0, stream>>>(Ym, p1, p2);
  bn_stats2<<<1, blk, 0, stream>>>(p1, p2, mu, rinv, 256);
  bn_spike_add<<<4096, blk, 0, stream>>>(Ym, mu, rinv, b2g, b2b, out, 256);
}